// Round 6
// baseline (264.304 us; speedup 1.0000x reference)
//
#include <hip/hip_runtime.h>
#include <hip/hip_bf16.h>
#include <cstdint>
#include <cstddef>

constexpr int B_ = 2, SQ_ = 2048, SK_ = 2048, H_ = 32, HK_ = 8, D_ = 128;
constexpr float SCALE_ = 0.08838834764831845f;  // 1/sqrt(128)

typedef __attribute__((ext_vector_type(4))) float f32x4;
typedef __attribute__((ext_vector_type(8))) short bf16x8;

__device__ __forceinline__ unsigned short f2bf(float f) {
  union { float f; uint32_t u; } v; v.f = f;
  uint32_t u = v.u;
  return (unsigned short)((u + 0x7FFFu + ((u >> 16) & 1u)) >> 16);  // RNE
}

__device__ __forceinline__ void gload16(const void* g, void* l) {
  __builtin_amdgcn_global_load_lds((const __attribute__((address_space(1))) void*)g,
                                   (__attribute__((address_space(3))) void*)l, 16, 0, 0);
}

// ---- sk_valid per batch (mask dtype sniffed at runtime)
__global__ void skv_kernel(const void* __restrict__ mask, int* __restrict__ skv_out) {
  const int b = blockIdx.x;
  const int tid = threadIdx.x;
  __shared__ int red[256];
  const uint32_t* mw = (const uint32_t*)mask;
  const uint32_t w0 = mw[0], w1 = mw[1];
  int cnt = 0;
  if (w0 > 1u) {  // uint8 bools
    const uint8_t* m = (const uint8_t*)mask + (size_t)b * SK_;
    for (int s = tid; s < SK_; s += 256) cnt += (m[s] != 0);
  } else if (w1 == 0u) {  // int64
    const uint32_t* m = mw + (size_t)b * SK_ * 2;
    for (int s = tid; s < SK_; s += 256) cnt += (m[2 * s] != 0);
  } else {  // int32
    const int* m = (const int*)mask + (size_t)b * SK_;
    for (int s = tid; s < SK_; s += 256) cnt += (m[s] != 0);
  }
  red[tid] = cnt;
  __syncthreads();
  for (int o = 128; o > 0; o >>= 1) {
    if (tid < o) red[tid] += red[tid + o];
    __syncthreads();
  }
  if (tid == 0) skv_out[b] = red[0];
}

// ---- mean of V over all SK keys (uniform-softmax degenerate rows)
__global__ void meanv_kernel(const float* __restrict__ kv, float* __restrict__ meanv) {
  const int blk = blockIdx.x;
  const int chunk = blk & 15;
  const int hk = (blk >> 4) & 7;
  const int b = blk >> 7;
  const int d = threadIdx.x;
  float sum = 0.0f;
  for (int i = 0; i < 128; ++i) {
    const int s = chunk * 128 + i;
    sum += kv[((((size_t)b * SK_ + s) * 2 + 1) * HK_ + hk) * D_ + d];
  }
  atomicAdd(meanv + ((size_t)b * HK_ + hk) * D_ + d, sum * (1.0f / (float)SK_));
}

// ---- K: f32 [b][s][0][hk][d] -> bf16 Kb [b][hk][s][d]
__global__ void convk(const float* __restrict__ kv, unsigned short* __restrict__ Kb) {
  const int b = blockIdx.z, hk = blockIdx.y;
  const int s = blockIdx.x * 16 + (threadIdx.x >> 4);
  const int dc = (threadIdx.x & 15) * 8;
  const float* src = kv + ((((size_t)b * SK_ + s) * 2 + 0) * HK_ + hk) * D_ + dc;
  f32x4 a0 = *(const f32x4*)src;
  f32x4 a1 = *(const f32x4*)(src + 4);
  bf16x8 t;
  t[0] = (short)f2bf(a0[0]); t[1] = (short)f2bf(a0[1]);
  t[2] = (short)f2bf(a0[2]); t[3] = (short)f2bf(a0[3]);
  t[4] = (short)f2bf(a1[0]); t[5] = (short)f2bf(a1[1]);
  t[6] = (short)f2bf(a1[2]); t[7] = (short)f2bf(a1[3]);
  *(bf16x8*)(Kb + ((size_t)(b * HK_ + hk) * SK_ + s) * D_ + dc) = t;
}

// ---- V: f32 [b][s][1][hk][d] -> bf16 VTb [b][hk][d][s] (transposed)
__global__ void convvt(const float* __restrict__ kv, unsigned short* __restrict__ VTb) {
  const int b = blockIdx.z, hk = blockIdx.y;
  const int s0 = blockIdx.x * 64;
  const int d = threadIdx.x & 127;
  const int sg = threadIdx.x >> 7;
  unsigned short vals[32];
#pragma unroll
  for (int i = 0; i < 32; ++i) {
    const int s = s0 + sg * 32 + i;
    vals[i] = f2bf(kv[((((size_t)b * SK_ + s) * 2 + 1) * HK_ + hk) * D_ + d]);
  }
  unsigned short* dst = VTb + ((size_t)(b * HK_ + hk) * D_ + d) * SK_ + s0 + sg * 32;
#pragma unroll
  for (int c = 0; c < 4; ++c) {
    bf16x8 t;
#pragma unroll
    for (int i = 0; i < 8; ++i) t[i] = (short)vals[c * 8 + i];
    *(bf16x8*)(dst + c * 8) = t;
  }
}

// ---- flash attention v6: 512 persistent blocks, queue of 1024 items (LPT)
__global__ __launch_bounds__(256, 2)
void flash6(const float* __restrict__ q, const unsigned short* __restrict__ Kb,
            const unsigned short* __restrict__ VTb, const int* __restrict__ skv_arr,
            const float* __restrict__ meanv, float* __restrict__ out,
            int* __restrict__ work_ctr) {
  const int tid = threadIdx.x;
  const int w = tid >> 6, l = tid & 63, lg = l >> 4, lr = l & 15;

  __shared__ char smem[40960];
  char* kc0 = smem;        char* kn0 = smem + 8192;
  char* vc0 = smem + 16384; char* vn0 = smem + 24576;
  char* pbuf = smem + 32768 + (w << 11);  // 2 KB per wave

  for (;;) {
    // ---- grab next work item (heaviest qtile first: greedy-LPT; 2 items/block avg)
    if (tid == 0) *(volatile int*)smem = atomicAdd(work_ctr, 1);
    __syncthreads();
    const int r = *(volatile int*)smem;
    __syncthreads();  // all read item before staging overwrites smem[0..3]
    if (r >= SQ_ / 128 * H_ * B_) break;

    const int qtile = 15 - (r >> 6);
    const int h = r & 31;
    const int b = (r >> 5) & 1;
    const int hk = h >> 2;
    const int t0 = qtile * 128;
    const int skv = skv_arr[b];

    char* kc = kc0; char* kn = kn0; char* vc = vc0; char* vn = vn0;

    // Q fragments: rows t0 + w*32 + rb*16 + lr
    bf16x8 qf[2][4];
#pragma unroll
    for (int rb = 0; rb < 2; ++rb) {
      const int trow = t0 + w * 32 + rb * 16 + lr;
      const float* qp = q + (((size_t)b * SQ_ + trow) * H_ + h) * D_;
#pragma unroll
      for (int kk = 0; kk < 4; ++kk) {
        f32x4 a0 = *(const f32x4*)(qp + kk * 32 + lg * 8);
        f32x4 a1 = *(const f32x4*)(qp + kk * 32 + lg * 8 + 4);
        bf16x8 t;
        t[0] = (short)f2bf(a0[0]); t[1] = (short)f2bf(a0[1]);
        t[2] = (short)f2bf(a0[2]); t[3] = (short)f2bf(a0[3]);
        t[4] = (short)f2bf(a1[0]); t[5] = (short)f2bf(a1[1]);
        t[6] = (short)f2bf(a1[2]); t[7] = (short)f2bf(a1[3]);
        qf[rb][kk] = t;
      }
    }

    f32x4 acc0[8], acc1[8];
#pragma unroll
    for (int i = 0; i < 8; ++i) { acc0[i] = (f32x4)0.0f; acc1[i] = (f32x4)0.0f; }
    float m0[4], l0[4], m1[4], l1[4];
#pragma unroll
    for (int rr = 0; rr < 4; ++rr) { m0[rr] = -1e30f; l0[rr] = 0.0f; m1[rr] = -1e30f; l1[rr] = 0.0f; }

    int n_allowed = t0 + 127 + skv - SQ_ + 1;
    if (n_allowed > skv) n_allowed = skv;
    const int nt = (n_allowed > 0) ? ((n_allowed + 31) >> 5) : 0;

    const char* kgb = (const char*)Kb + ((size_t)(b * HK_ + hk)) * SK_ * D_ * 2;
    const char* vgb = (const char*)VTb + ((size_t)(b * HK_ + hk)) * (size_t)D_ * SK_ * 2;

    auto stage = [&](char* kdst, char* vdst, int s0) {
      const char* kt = kgb + (size_t)s0 * 256;
#pragma unroll
      for (int i = 0; i < 2; ++i) {
        const int c8 = w * 2 + i;
        const int beta = c8 * 1024 + l * 16;
        const int row = beta >> 8;
        gload16(kt + (beta ^ ((row & 7) << 4)), kdst + c8 * 1024);
      }
      const char* vt = vgb + s0 * 2;
#pragma unroll
      for (int i = 0; i < 2; ++i) {
        const int c8 = w * 2 + i;
        const int beta = c8 * 1024 + l * 16;
        const int lam = beta ^ (((beta >> 7) & 7) << 4);
        const int d = lam >> 6, keyb = lam & 63;
        gload16(vt + (size_t)d * (SK_ * 2) + keyb, vdst + c8 * 1024);
      }
    };

    asm volatile("s_waitcnt vmcnt(0)" ::: "memory");
    if (nt > 0) stage(kc, vc, 0);

    for (int j = 0; j < nt; ++j) {
      if (j + 1 < nt) {
        stage(kn, vn, (j + 1) * 32);
        asm volatile("s_waitcnt vmcnt(4)" ::: "memory");
      } else {
        asm volatile("s_waitcnt vmcnt(0)" ::: "memory");
      }
      __builtin_amdgcn_s_barrier();

      const int s0 = j * 32;
      // ---- S = Q K^T  (2 row-blocks x 32 keys per wave)
      f32x4 sc0[2], sc1[2];
      sc0[0] = (f32x4)0.0f; sc0[1] = (f32x4)0.0f;
      sc1[0] = (f32x4)0.0f; sc1[1] = (f32x4)0.0f;
#pragma unroll
      for (int c = 0; c < 2; ++c) {
        const int key = c * 16 + lr;
        const int kx = (key & 7) << 4;
#pragma unroll
        for (int kk = 0; kk < 4; ++kk) {
          const int byte = (key << 8) + ((kk * 32 + lg * 8) << 1);
          bf16x8 kf = *(const bf16x8*)(kc + (byte ^ kx));
          sc0[c] = __builtin_amdgcn_mfma_f32_16x16x32_bf16(qf[0][kk], kf, sc0[c], 0, 0, 0);
          sc1[c] = __builtin_amdgcn_mfma_f32_16x16x32_bf16(qf[1][kk], kf, sc1[c], 0, 0, 0);
        }
      }

      // ---- mask + online softmax per row-block
      float al0[4], al1[4];
      auto softmax_rb = [&](f32x4* sc, float* mr, float* lrr, float* al, int tbase) {
#pragma unroll
        for (int rr = 0; rr < 4; ++rr) {
          const int lim = tbase + lg * 4 + rr + skv - SQ_;
          float mx = -1e30f;
#pragma unroll
          for (int c = 0; c < 2; ++c) {
            const int key = s0 + c * 16 + lr;
            float sv = (key <= lim) ? sc[c][rr] * SCALE_ : -1e30f;
            sc[c][rr] = sv;
            mx = fmaxf(mx, sv);
          }
          mx = fmaxf(mx, __shfl_xor(mx, 1, 16));
          mx = fmaxf(mx, __shfl_xor(mx, 2, 16));
          mx = fmaxf(mx, __shfl_xor(mx, 4, 16));
          mx = fmaxf(mx, __shfl_xor(mx, 8, 16));
          const float mn = fmaxf(mr[rr], mx);
          al[rr] = __expf(mr[rr] - mn);
          mr[rr] = mn;
          float ps = 0.0f;
#pragma unroll
          for (int c = 0; c < 2; ++c) {
            const float p = __expf(sc[c][rr] - mn);
            sc[c][rr] = p;
            ps += p;
          }
          ps += __shfl_xor(ps, 1, 16);
          ps += __shfl_xor(ps, 2, 16);
          ps += __shfl_xor(ps, 4, 16);
          ps += __shfl_xor(ps, 8, 16);
          lrr[rr] = lrr[rr] * al[rr] + ps;
        }
      };
      softmax_rb(sc0, m0, l0, al0, t0 + w * 32);
      softmax_rb(sc1, m1, l1, al1, t0 + w * 32 + 16);

#pragma unroll
      for (int dd = 0; dd < 8; ++dd)
#pragma unroll
        for (int rr = 0; rr < 4; ++rr) { acc0[dd][rr] *= al0[rr]; acc1[dd][rr] *= al1[rr]; }

      // ---- P -> LDS (bf16, swizzled; both row-blocks)
#pragma unroll
      for (int rb = 0; rb < 2; ++rb) {
        const f32x4* sc = rb ? sc1 : sc0;
#pragma unroll
        for (int c = 0; c < 2; ++c)
#pragma unroll
          for (int rr = 0; rr < 4; ++rr) {
            const int prow = rb * 16 + lg * 4 + rr;
            const int lam = prow * 64 + (c * 16 + lr) * 2;
            const int byte = lam ^ (((lam >> 7) & 7) << 4);
            *(unsigned short*)(pbuf + byte) = f2bf(sc[c][rr]);
          }
      }
      asm volatile("s_waitcnt lgkmcnt(0)" ::: "memory");
      __builtin_amdgcn_sched_barrier(0);

      // ---- O += P V
      {
        const int lam0 = lr * 64 + lg * 16;
        bf16x8 pf0 = *(const bf16x8*)(pbuf + (lam0 ^ (((lam0 >> 7) & 7) << 4)));
        const int lam1 = (16 + lr) * 64 + lg * 16;
        bf16x8 pf1 = *(const bf16x8*)(pbuf + (lam1 ^ (((lam1 >> 7) & 7) << 4)));
#pragma unroll
        for (int dd = 0; dd < 8; ++dd) {
          const int d = dd * 16 + lr;
          const int lam = d * 64 + lg * 16;
          bf16x8 vf = *(const bf16x8*)(vc + (lam ^ (((lam >> 7) & 7) << 4)));
          acc0[dd] = __builtin_amdgcn_mfma_f32_16x16x32_bf16(pf0, vf, acc0[dd], 0, 0, 0);
          acc1[dd] = __builtin_amdgcn_mfma_f32_16x16x32_bf16(pf1, vf, acc1[dd], 0, 0, 0);
        }
      }
      asm volatile("" ::: "memory");
      __builtin_amdgcn_s_barrier();
      { char* t = kc; kc = kn; kn = t; t = vc; vc = vn; vn = t; }
    }

    // ---- epilogue
    const float* mp = meanv + ((size_t)(b * HK_ + hk)) * D_;
#pragma unroll
    for (int rb = 0; rb < 2; ++rb) {
      const f32x4* acc = rb ? acc1 : acc0;
      const float* lrr = rb ? l1 : l0;
#pragma unroll
      for (int rr = 0; rr < 4; ++rr) {
        const int t_r = t0 + w * 32 + rb * 16 + lg * 4 + rr;
        const bool deg = (t_r + skv - SQ_) < 0;
        const float inv = 1.0f / lrr[rr];
        float* op = out + (((size_t)b * SQ_ + t_r) * H_ + h) * D_;
#pragma unroll
        for (int dd = 0; dd < 8; ++dd) {
          const int d = dd * 16 + lr;
          op[d] = deg ? mp[d] : acc[dd][rr] * inv;
        }
      }
    }
    __syncthreads();  // all waves done with LDS/regs before next grab
  }
}

extern "C" void kernel_launch(void* const* d_in, const int* in_sizes, int n_in,
                              void* d_out, int out_size, void* d_ws, size_t ws_size,
                              hipStream_t stream) {
  const float* q = (const float*)d_in[0];
  const float* kv = (const float*)d_in[1];
  const void* mask = d_in[2];
  float* out = (float*)d_out;

  const size_t KB_OFF = 0;
  const size_t VT_OFF = 8ull * 1024 * 1024;
  const size_t MV_OFF = 16ull * 1024 * 1024;
  unsigned short* Kb = (unsigned short*)((char*)d_ws + KB_OFF);
  unsigned short* VTb = (unsigned short*)((char*)d_ws + VT_OFF);
  float* meanv = (float*)((char*)d_ws + MV_OFF);
  int* skv = (int*)((char*)d_ws + MV_OFF + 8192);
  int* work_ctr = (int*)((char*)d_ws + MV_OFF + 8192 + 64);

  hipMemsetAsync((char*)d_ws + MV_OFF, 0, 8192 + 128, stream);
  skv_kernel<<<B_, 256, 0, stream>>>(mask, skv);
  convk<<<dim3(SK_ / 16, HK_, B_), 256, 0, stream>>>(kv, Kb);
  convvt<<<dim3(SK_ / 64, HK_, B_), 256, 0, stream>>>(kv, VTb);
  meanv_kernel<<<B_ * HK_ * 16, 128, 0, stream>>>(kv, meanv);
  flash6<<<dim3(512), 256, 0, stream>>>(q, Kb, VTb, skv, meanv, out, work_ctr);
}

// Round 7
// 194.304 us; speedup vs baseline: 1.3603x; 1.3603x over previous
//
#include <hip/hip_runtime.h>
#include <hip/hip_bf16.h>
#include <cstdint>
#include <cstddef>

constexpr int B_ = 2, SQ_ = 2048, SK_ = 2048, H_ = 32, HK_ = 8, D_ = 128;
constexpr float SCALE_ = 0.08838834764831845f;  // 1/sqrt(128)

typedef __attribute__((ext_vector_type(4))) float f32x4;
typedef __attribute__((ext_vector_type(8))) short bf16x8;

__device__ __forceinline__ unsigned short f2bf(float f) {
  union { float f; uint32_t u; } v; v.f = f;
  uint32_t u = v.u;
  return (unsigned short)((u + 0x7FFFu + ((u >> 16) & 1u)) >> 16);  // RNE
}

__device__ __forceinline__ void gload16(const void* g, void* l) {
  __builtin_amdgcn_global_load_lds((const __attribute__((address_space(1))) void*)g,
                                   (__attribute__((address_space(3))) void*)l, 16, 0, 0);
}

// ---- sk_valid per batch (mask dtype sniffed at runtime)
__global__ void skv_kernel(const void* __restrict__ mask, int* __restrict__ skv_out) {
  const int b = blockIdx.x;
  const int tid = threadIdx.x;
  __shared__ int red[256];
  const uint32_t* mw = (const uint32_t*)mask;
  const uint32_t w0 = mw[0], w1 = mw[1];
  int cnt = 0;
  if (w0 > 1u) {  // uint8 bools
    const uint8_t* m = (const uint8_t*)mask + (size_t)b * SK_;
    for (int s = tid; s < SK_; s += 256) cnt += (m[s] != 0);
  } else if (w1 == 0u) {  // int64
    const uint32_t* m = mw + (size_t)b * SK_ * 2;
    for (int s = tid; s < SK_; s += 256) cnt += (m[2 * s] != 0);
  } else {  // int32
    const int* m = (const int*)mask + (size_t)b * SK_;
    for (int s = tid; s < SK_; s += 256) cnt += (m[s] != 0);
  }
  red[tid] = cnt;
  __syncthreads();
  for (int o = 128; o > 0; o >>= 1) {
    if (tid < o) red[tid] += red[tid + o];
    __syncthreads();
  }
  if (tid == 0) skv_out[b] = red[0];
}

// ---- mean of V over all SK keys (uniform-softmax degenerate rows)
__global__ void meanv_kernel(const float* __restrict__ kv, float* __restrict__ meanv) {
  const int blk = blockIdx.x;
  const int chunk = blk & 15;
  const int hk = (blk >> 4) & 7;
  const int b = blk >> 7;
  const int d = threadIdx.x;
  float sum = 0.0f;
  for (int i = 0; i < 128; ++i) {
    const int s = chunk * 128 + i;
    sum += kv[((((size_t)b * SK_ + s) * 2 + 1) * HK_ + hk) * D_ + d];
  }
  atomicAdd(meanv + ((size_t)b * HK_ + hk) * D_ + d, sum * (1.0f / (float)SK_));
}

// ---- K: f32 [b][s][0][hk][d] -> bf16 Kb [b][hk][s][d]
__global__ void convk(const float* __restrict__ kv, unsigned short* __restrict__ Kb) {
  const int b = blockIdx.z, hk = blockIdx.y;
  const int s = blockIdx.x * 16 + (threadIdx.x >> 4);
  const int dc = (threadIdx.x & 15) * 8;
  const float* src = kv + ((((size_t)b * SK_ + s) * 2 + 0) * HK_ + hk) * D_ + dc;
  f32x4 a0 = *(const f32x4*)src;
  f32x4 a1 = *(const f32x4*)(src + 4);
  bf16x8 t;
  t[0] = (short)f2bf(a0[0]); t[1] = (short)f2bf(a0[1]);
  t[2] = (short)f2bf(a0[2]); t[3] = (short)f2bf(a0[3]);
  t[4] = (short)f2bf(a1[0]); t[5] = (short)f2bf(a1[1]);
  t[6] = (short)f2bf(a1[2]); t[7] = (short)f2bf(a1[3]);
  *(bf16x8*)(Kb + ((size_t)(b * HK_ + hk) * SK_ + s) * D_ + dc) = t;
}

// ---- V: f32 [b][s][1][hk][d] -> bf16 VTb [b][hk][d][s] (transposed)
__global__ void convvt(const float* __restrict__ kv, unsigned short* __restrict__ VTb) {
  const int b = blockIdx.z, hk = blockIdx.y;
  const int s0 = blockIdx.x * 64;
  const int d = threadIdx.x & 127;
  const int sg = threadIdx.x >> 7;
  unsigned short vals[32];
#pragma unroll
  for (int i = 0; i < 32; ++i) {
    const int s = s0 + sg * 32 + i;
    vals[i] = f2bf(kv[((((size_t)b * SK_ + s) * 2 + 1) * HK_ + hk) * D_ + d]);
  }
  unsigned short* dst = VTb + ((size_t)(b * HK_ + hk) * D_ + d) * SK_ + s0 + sg * 32;
#pragma unroll
  for (int c = 0; c < 4; ++c) {
    bf16x8 t;
#pragma unroll
    for (int i = 0; i < 8; ++i) t[i] = (short)vals[c * 8 + i];
    *(bf16x8*)(dst + c * 8) = t;
  }
}

// ---- flash attention v7: swapped QK^T -> in-register softmax
__global__ __launch_bounds__(256, 2)
void flash7(const float* __restrict__ q, const unsigned short* __restrict__ Kb,
            const unsigned short* __restrict__ VTb, const int* __restrict__ skv_arr,
            const float* __restrict__ meanv, float* __restrict__ out,
            int* __restrict__ work_ctr) {
  const int tid = threadIdx.x;
  const int w = tid >> 6, l = tid & 63, lg = l >> 4, lr = l & 15;

  __shared__ char smem[40960];
  char* kc0 = smem;        char* kn0 = smem + 8192;
  char* vc0 = smem + 16384; char* vn0 = smem + 24576;
  char* pbuf = smem + 32768 + (w << 11);  // 2 KB per wave

  for (;;) {
    // ---- grab next work item (heaviest qtile first: greedy-LPT)
    if (tid == 0) *(volatile int*)smem = atomicAdd(work_ctr, 1);
    __syncthreads();
    const int r = *(volatile int*)smem;
    __syncthreads();  // all read item before staging overwrites smem[0..3]
    if (r >= SQ_ / 128 * H_ * B_) break;

    const int qtile = 15 - (r >> 6);
    const int h = r & 31;
    const int b = (r >> 5) & 1;
    const int hk = h >> 2;
    const int t0 = qtile * 128;
    const int skv = skv_arr[b];

    char* kc = kc0; char* kn = kn0; char* vc = vc0; char* vn = vn0;

    // Q B-fragments: col(q)=lr, k-chunk kk, k-sub lg*8
    bf16x8 qf[2][4];
#pragma unroll
    for (int rb = 0; rb < 2; ++rb) {
      const int trow = t0 + w * 32 + rb * 16 + lr;
      const float* qp = q + (((size_t)b * SQ_ + trow) * H_ + h) * D_;
#pragma unroll
      for (int kk = 0; kk < 4; ++kk) {
        f32x4 a0 = *(const f32x4*)(qp + kk * 32 + lg * 8);
        f32x4 a1 = *(const f32x4*)(qp + kk * 32 + lg * 8 + 4);
        bf16x8 t;
        t[0] = (short)f2bf(a0[0]); t[1] = (short)f2bf(a0[1]);
        t[2] = (short)f2bf(a0[2]); t[3] = (short)f2bf(a0[3]);
        t[4] = (short)f2bf(a1[0]); t[5] = (short)f2bf(a1[1]);
        t[6] = (short)f2bf(a1[2]); t[7] = (short)f2bf(a1[3]);
        qf[rb][kk] = t;
      }
    }

    f32x4 acc0[8], acc1[8];
#pragma unroll
    for (int i = 0; i < 8; ++i) { acc0[i] = (f32x4)0.0f; acc1[i] = (f32x4)0.0f; }
    // running max / sum per q-row (q = lr), consistent across the 4 lane-groups
    float m_[2], l_[2];
#pragma unroll
    for (int rb = 0; rb < 2; ++rb) { m_[rb] = -1e30f; l_[rb] = 0.0f; }

    int n_allowed = t0 + 127 + skv - SQ_ + 1;
    if (n_allowed > skv) n_allowed = skv;
    const int nt = (n_allowed > 0) ? ((n_allowed + 31) >> 5) : 0;

    const char* kgb = (const char*)Kb + ((size_t)(b * HK_ + hk)) * SK_ * D_ * 2;
    const char* vgb = (const char*)VTb + ((size_t)(b * HK_ + hk)) * (size_t)D_ * SK_ * 2;

    auto stage = [&](char* kdst, char* vdst, int s0) {
      const char* kt = kgb + (size_t)s0 * 256;
#pragma unroll
      for (int i = 0; i < 2; ++i) {
        const int c8 = w * 2 + i;
        const int beta = c8 * 1024 + l * 16;
        const int row = beta >> 8;
        gload16(kt + (beta ^ ((row & 7) << 4)), kdst + c8 * 1024);
      }
      const char* vt = vgb + s0 * 2;
#pragma unroll
      for (int i = 0; i < 2; ++i) {
        const int c8 = w * 2 + i;
        const int beta = c8 * 1024 + l * 16;
        const int lam = beta ^ (((beta >> 7) & 7) << 4);
        const int d = lam >> 6, keyb = lam & 63;
        gload16(vt + (size_t)d * (SK_ * 2) + keyb, vdst + c8 * 1024);
      }
    };

    asm volatile("s_waitcnt vmcnt(0)" ::: "memory");
    if (nt > 0) stage(kc, vc, 0);

    for (int j = 0; j < nt; ++j) {
      if (j + 1 < nt) {
        stage(kn, vn, (j + 1) * 32);
        asm volatile("s_waitcnt vmcnt(4)" ::: "memory");
      } else {
        asm volatile("s_waitcnt vmcnt(0)" ::: "memory");
      }
      __builtin_amdgcn_s_barrier();

      const int s0 = j * 32;
      // ---- S^T = K Q^T (swapped): sc[rb][c][r] = S[key = s0+c*16+lg*4+r][q = rb*16+lr]
      f32x4 sc[2][2];
      sc[0][0] = (f32x4)0.0f; sc[0][1] = (f32x4)0.0f;
      sc[1][0] = (f32x4)0.0f; sc[1][1] = (f32x4)0.0f;
#pragma unroll
      for (int c = 0; c < 2; ++c) {
        const int key = c * 16 + lr;
        const int kx = (key & 7) << 4;
#pragma unroll
        for (int kk = 0; kk < 4; ++kk) {
          const int byte = (key << 8) + ((kk * 32 + lg * 8) << 1);
          bf16x8 kf = *(const bf16x8*)(kc + (byte ^ kx));
          sc[0][c] = __builtin_amdgcn_mfma_f32_16x16x32_bf16(kf, qf[0][kk], sc[0][c], 0, 0, 0);
          sc[1][c] = __builtin_amdgcn_mfma_f32_16x16x32_bf16(kf, qf[1][kk], sc[1][c], 0, 0, 0);
        }
      }

      // ---- mask + online softmax, in-register (row = q = lr per lane)
      const int kbase = s0 + (lg << 2);
      float al_[2];
#pragma unroll
      for (int rb = 0; rb < 2; ++rb) {
        const int lim = t0 + w * 32 + rb * 16 + lr + skv - SQ_;
        float mx = -1e30f;
#pragma unroll
        for (int c = 0; c < 2; ++c)
#pragma unroll
          for (int rr = 0; rr < 4; ++rr) {
            const int key = kbase + c * 16 + rr;
            float sv = (key <= lim) ? sc[rb][c][rr] * SCALE_ : -1e30f;
            sc[rb][c][rr] = sv;
            mx = fmaxf(mx, sv);
          }
        mx = fmaxf(mx, __shfl_xor(mx, 16));
        mx = fmaxf(mx, __shfl_xor(mx, 32));
        const float mn = fmaxf(m_[rb], mx);
        al_[rb] = __expf(m_[rb] - mn);
        m_[rb] = mn;
        float ps = 0.0f;
#pragma unroll
        for (int c = 0; c < 2; ++c)
#pragma unroll
          for (int rr = 0; rr < 4; ++rr) {
            const float p = __expf(sc[rb][c][rr] - mn);
            sc[rb][c][rr] = p;
            ps += p;
          }
        ps += __shfl_xor(ps, 16);
        ps += __shfl_xor(ps, 32);
        l_[rb] = l_[rb] * al_[rb] + ps;
      }

      // ---- rescale acc: alpha lives at q=lr; acc needs q=lg*4+rr
      float alq0[4], alq1[4];
#pragma unroll
      for (int rr = 0; rr < 4; ++rr) {
        alq0[rr] = __shfl(al_[0], lg * 4 + rr, 16);
        alq1[rr] = __shfl(al_[1], lg * 4 + rr, 16);
      }
#pragma unroll
      for (int dd = 0; dd < 8; ++dd)
#pragma unroll
        for (int rr = 0; rr < 4; ++rr) { acc0[dd][rr] *= alq0[rr]; acc1[dd][rr] *= alq1[rr]; }

      // ---- P -> LDS (packed b64 writes, swizzled): P[prow=rb*16+lr][key=c*16+lg*4+r]
#pragma unroll
      for (int rb = 0; rb < 2; ++rb) {
        const int prow = rb * 16 + lr;
#pragma unroll
        for (int c = 0; c < 2; ++c) {
          const uint32_t d0 = (uint32_t)f2bf(sc[rb][c][0]) | ((uint32_t)f2bf(sc[rb][c][1]) << 16);
          const uint32_t d1 = (uint32_t)f2bf(sc[rb][c][2]) | ((uint32_t)f2bf(sc[rb][c][3]) << 16);
          const int lam = prow * 64 + (c * 16 + (lg << 2)) * 2;
          const int byte = lam ^ (((lam >> 7) & 7) << 4);
          *(unsigned long long*)(pbuf + byte) =
              (unsigned long long)d0 | ((unsigned long long)d1 << 32);
        }
      }
      asm volatile("s_waitcnt lgkmcnt(0)" ::: "memory");
      __builtin_amdgcn_sched_barrier(0);

      // ---- O += P V
      {
        const int lam0 = lr * 64 + lg * 16;
        bf16x8 pf0 = *(const bf16x8*)(pbuf + (lam0 ^ (((lam0 >> 7) & 7) << 4)));
        const int lam1 = (16 + lr) * 64 + lg * 16;
        bf16x8 pf1 = *(const bf16x8*)(pbuf + (lam1 ^ (((lam1 >> 7) & 7) << 4)));
#pragma unroll
        for (int dd = 0; dd < 8; ++dd) {
          const int d = dd * 16 + lr;
          const int lam = d * 64 + lg * 16;
          bf16x8 vf = *(const bf16x8*)(vc + (lam ^ (((lam >> 7) & 7) << 4)));
          acc0[dd] = __builtin_amdgcn_mfma_f32_16x16x32_bf16(pf0, vf, acc0[dd], 0, 0, 0);
          acc1[dd] = __builtin_amdgcn_mfma_f32_16x16x32_bf16(pf1, vf, acc1[dd], 0, 0, 0);
        }
      }
      asm volatile("" ::: "memory");
      __builtin_amdgcn_s_barrier();
      { char* t = kc; kc = kn; kn = t; t = vc; vc = vn; vn = t; }
    }

    // ---- epilogue (l_ lives at q=lr; acc rows are q=lg*4+rr)
    const float* mp = meanv + ((size_t)(b * HK_ + hk)) * D_;
#pragma unroll
    for (int rb = 0; rb < 2; ++rb) {
      const f32x4* acc = rb ? acc1 : acc0;
      const float lsrc = rb ? l_[1] : l_[0];
#pragma unroll
      for (int rr = 0; rr < 4; ++rr) {
        const float lq = __shfl(lsrc, lg * 4 + rr, 16);
        const int t_r = t0 + w * 32 + rb * 16 + lg * 4 + rr;
        const bool deg = (t_r + skv - SQ_) < 0;
        const float inv = 1.0f / lq;
        float* op = out + (((size_t)b * SQ_ + t_r) * H_ + h) * D_;
#pragma unroll
        for (int dd = 0; dd < 8; ++dd) {
          const int d = dd * 16 + lr;
          op[d] = deg ? mp[d] : acc[dd][rr] * inv;
        }
      }
    }
    __syncthreads();  // all waves done with LDS/regs before next grab
  }
}

extern "C" void kernel_launch(void* const* d_in, const int* in_sizes, int n_in,
                              void* d_out, int out_size, void* d_ws, size_t ws_size,
                              hipStream_t stream) {
  const float* q = (const float*)d_in[0];
  const float* kv = (const float*)d_in[1];
  const void* mask = d_in[2];
  float* out = (float*)d_out;

  const size_t KB_OFF = 0;
  const size_t VT_OFF = 8ull * 1024 * 1024;
  const size_t MV_OFF = 16ull * 1024 * 1024;
  unsigned short* Kb = (unsigned short*)((char*)d_ws + KB_OFF);
  unsigned short* VTb = (unsigned short*)((char*)d_ws + VT_OFF);
  float* meanv = (float*)((char*)d_ws + MV_OFF);
  int* skv = (int*)((char*)d_ws + MV_OFF + 8192);
  int* work_ctr = (int*)((char*)d_ws + MV_OFF + 8192 + 64);

  hipMemsetAsync((char*)d_ws + MV_OFF, 0, 8192 + 128, stream);
  skv_kernel<<<B_, 256, 0, stream>>>(mask, skv);
  convk<<<dim3(SK_ / 16, HK_, B_), 256, 0, stream>>>(kv, Kb);
  convvt<<<dim3(SK_ / 64, HK_, B_), 256, 0, stream>>>(kv, VTb);
  meanv_kernel<<<B_ * HK_ * 16, 128, 0, stream>>>(kv, meanv);
  flash7<<<dim3(512), 256, 0, stream>>>(q, Kb, VTb, skv, meanv, out, work_ctr);
}

// Round 8
// 190.641 us; speedup vs baseline: 1.3864x; 1.0192x over previous
//
#include <hip/hip_runtime.h>
#include <hip/hip_bf16.h>
#include <cstdint>
#include <cstddef>

constexpr int B_ = 2, SQ_ = 2048, SK_ = 2048, H_ = 32, HK_ = 8, D_ = 128;
constexpr float SCALE_ = 0.08838834764831845f;  // 1/sqrt(128)

typedef __attribute__((ext_vector_type(4))) float f32x4;
typedef __attribute__((ext_vector_type(8))) short bf16x8;
typedef __attribute__((ext_vector_type(4))) short bf16x4;

__device__ __forceinline__ unsigned short f2bf(float f) {
  union { float f; uint32_t u; } v; v.f = f;
  uint32_t u = v.u;
  return (unsigned short)((u + 0x7FFFu + ((u >> 16) & 1u)) >> 16);  // RNE
}

__device__ __forceinline__ void gload16(const void* g, void* l) {
  __builtin_amdgcn_global_load_lds((const __attribute__((address_space(1))) void*)g,
                                   (__attribute__((address_space(3))) void*)l, 16, 0, 0);
}

// K=16 MFMA: D[m=q:16][n=d:16] += A[m][k:16] * B[n][k:16], fragments k = lg*4+j.
__device__ __forceinline__ f32x4 mfma_k16(bf16x4 a, bf16x4 b, f32x4 c) {
#if __has_builtin(__builtin_amdgcn_mfma_f32_16x16x16bf16_1k)
  return __builtin_amdgcn_mfma_f32_16x16x16bf16_1k(a, b, c, 0, 0, 0);
#else
  // zero-padded K=32: both operands put real data in j=0..3 of each lane group
  bf16x8 a8 = {a[0], a[1], a[2], a[3], 0, 0, 0, 0};
  bf16x8 b8 = {b[0], b[1], b[2], b[3], 0, 0, 0, 0};
  return __builtin_amdgcn_mfma_f32_16x16x32_bf16(a8, b8, c, 0, 0, 0);
#endif
}

// ---- sk_valid per batch (mask dtype sniffed at runtime)
__global__ void skv_kernel(const void* __restrict__ mask, int* __restrict__ skv_out) {
  const int b = blockIdx.x;
  const int tid = threadIdx.x;
  __shared__ int red[256];
  const uint32_t* mw = (const uint32_t*)mask;
  const uint32_t w0 = mw[0], w1 = mw[1];
  int cnt = 0;
  if (w0 > 1u) {  // uint8 bools
    const uint8_t* m = (const uint8_t*)mask + (size_t)b * SK_;
    for (int s = tid; s < SK_; s += 256) cnt += (m[s] != 0);
  } else if (w1 == 0u) {  // int64
    const uint32_t* m = mw + (size_t)b * SK_ * 2;
    for (int s = tid; s < SK_; s += 256) cnt += (m[2 * s] != 0);
  } else {  // int32
    const int* m = (const int*)mask + (size_t)b * SK_;
    for (int s = tid; s < SK_; s += 256) cnt += (m[s] != 0);
  }
  red[tid] = cnt;
  __syncthreads();
  for (int o = 128; o > 0; o >>= 1) {
    if (tid < o) red[tid] += red[tid + o];
    __syncthreads();
  }
  if (tid == 0) skv_out[b] = red[0];
}

// ---- mean of V over all SK keys (uniform-softmax degenerate rows)
__global__ void meanv_kernel(const float* __restrict__ kv, float* __restrict__ meanv) {
  const int blk = blockIdx.x;
  const int chunk = blk & 15;
  const int hk = (blk >> 4) & 7;
  const int b = blk >> 7;
  const int d = threadIdx.x;
  float sum = 0.0f;
  for (int i = 0; i < 128; ++i) {
    const int s = chunk * 128 + i;
    sum += kv[((((size_t)b * SK_ + s) * 2 + 1) * HK_ + hk) * D_ + d];
  }
  atomicAdd(meanv + ((size_t)b * HK_ + hk) * D_ + d, sum * (1.0f / (float)SK_));
}

// ---- K: f32 [b][s][0][hk][d] -> bf16 Kb [b][hk][s][d]
__global__ void convk(const float* __restrict__ kv, unsigned short* __restrict__ Kb) {
  const int b = blockIdx.z, hk = blockIdx.y;
  const int s = blockIdx.x * 16 + (threadIdx.x >> 4);
  const int dc = (threadIdx.x & 15) * 8;
  const float* src = kv + ((((size_t)b * SK_ + s) * 2 + 0) * HK_ + hk) * D_ + dc;
  f32x4 a0 = *(const f32x4*)src;
  f32x4 a1 = *(const f32x4*)(src + 4);
  bf16x8 t;
  t[0] = (short)f2bf(a0[0]); t[1] = (short)f2bf(a0[1]);
  t[2] = (short)f2bf(a0[2]); t[3] = (short)f2bf(a0[3]);
  t[4] = (short)f2bf(a1[0]); t[5] = (short)f2bf(a1[1]);
  t[6] = (short)f2bf(a1[2]); t[7] = (short)f2bf(a1[3]);
  *(bf16x8*)(Kb + ((size_t)(b * HK_ + hk) * SK_ + s) * D_ + dc) = t;
}

// ---- V: f32 [b][s][1][hk][d] -> bf16 VTb [b][hk][d][s] (transposed)
__global__ void convvt(const float* __restrict__ kv, unsigned short* __restrict__ VTb) {
  const int b = blockIdx.z, hk = blockIdx.y;
  const int s0 = blockIdx.x * 64;
  const int d = threadIdx.x & 127;
  const int sg = threadIdx.x >> 7;
  unsigned short vals[32];
#pragma unroll
  for (int i = 0; i < 32; ++i) {
    const int s = s0 + sg * 32 + i;
    vals[i] = f2bf(kv[((((size_t)b * SK_ + s) * 2 + 1) * HK_ + hk) * D_ + d]);
  }
  unsigned short* dst = VTb + ((size_t)(b * HK_ + hk) * D_ + d) * SK_ + s0 + sg * 32;
#pragma unroll
  for (int c = 0; c < 4; ++c) {
    bf16x8 t;
#pragma unroll
    for (int i = 0; i < 8; ++i) t[i] = (short)vals[c * 8 + i];
    *(bf16x8*)(dst + c * 8) = t;
  }
}

// ---- flash attention v8: in-register P (K=16 PV), 32KB LDS, 4 blocks/CU
__global__ __launch_bounds__(256, 2)
void flash8(const float* __restrict__ q, const unsigned short* __restrict__ Kb,
            const unsigned short* __restrict__ VTb, const int* __restrict__ skv_arr,
            const float* __restrict__ meanv, float* __restrict__ out,
            int* __restrict__ work_ctr) {
  const int tid = threadIdx.x;
  const int w = tid >> 6, l = tid & 63, lg = l >> 4, lr = l & 15;

  __shared__ char smem[32768];
  char* kc0 = smem;         char* kn0 = smem + 8192;
  char* vc0 = smem + 16384; char* vn0 = smem + 24576;

  for (;;) {
    // ---- grab next work item (heaviest qtile first)
    if (tid == 0) *(volatile int*)smem = atomicAdd(work_ctr, 1);
    __syncthreads();
    const int r = *(volatile int*)smem;
    __syncthreads();  // all read item before staging overwrites smem[0..3]
    if (r >= SQ_ / 128 * H_ * B_) break;

    const int qtile = 15 - (r >> 6);
    const int h = r & 31;
    const int b = (r >> 5) & 1;
    const int hk = h >> 2;
    const int t0 = qtile * 128;
    const int skv = skv_arr[b];

    char* kc = kc0; char* kn = kn0; char* vc = vc0; char* vn = vn0;

    // Q B-fragments for swapped QK^T: col(q)=lr, k-chunk kk, k-sub lg*8
    bf16x8 qf[2][4];
#pragma unroll
    for (int rb = 0; rb < 2; ++rb) {
      const int trow = t0 + w * 32 + rb * 16 + lr;
      const float* qp = q + (((size_t)b * SQ_ + trow) * H_ + h) * D_;
#pragma unroll
      for (int kk = 0; kk < 4; ++kk) {
        f32x4 a0 = *(const f32x4*)(qp + kk * 32 + lg * 8);
        f32x4 a1 = *(const f32x4*)(qp + kk * 32 + lg * 8 + 4);
        bf16x8 t;
        t[0] = (short)f2bf(a0[0]); t[1] = (short)f2bf(a0[1]);
        t[2] = (short)f2bf(a0[2]); t[3] = (short)f2bf(a0[3]);
        t[4] = (short)f2bf(a1[0]); t[5] = (short)f2bf(a1[1]);
        t[6] = (short)f2bf(a1[2]); t[7] = (short)f2bf(a1[3]);
        qf[rb][kk] = t;
      }
    }

    f32x4 acc0[8], acc1[8];
#pragma unroll
    for (int i = 0; i < 8; ++i) { acc0[i] = (f32x4)0.0f; acc1[i] = (f32x4)0.0f; }
    float m_[2], l_[2];
#pragma unroll
    for (int rb = 0; rb < 2; ++rb) { m_[rb] = -1e30f; l_[rb] = 0.0f; }

    int n_allowed = t0 + 127 + skv - SQ_ + 1;
    if (n_allowed > skv) n_allowed = skv;
    const int nt = (n_allowed > 0) ? ((n_allowed + 31) >> 5) : 0;

    const char* kgb = (const char*)Kb + ((size_t)(b * HK_ + hk)) * SK_ * D_ * 2;
    const char* vgb = (const char*)VTb + ((size_t)(b * HK_ + hk)) * (size_t)D_ * SK_ * 2;

    auto stage = [&](char* kdst, char* vdst, int s0) {
      const char* kt = kgb + (size_t)s0 * 256;
#pragma unroll
      for (int i = 0; i < 2; ++i) {
        const int c8 = w * 2 + i;
        const int beta = c8 * 1024 + l * 16;
        const int row = beta >> 8;
        gload16(kt + (beta ^ ((row & 7) << 4)), kdst + c8 * 1024);
      }
      const char* vt = vgb + s0 * 2;
#pragma unroll
      for (int i = 0; i < 2; ++i) {
        const int c8 = w * 2 + i;
        const int beta = c8 * 1024 + l * 16;
        const int lam = beta ^ (((beta >> 7) & 7) << 4);
        const int d = lam >> 6, keyb = lam & 63;
        gload16(vt + (size_t)d * (SK_ * 2) + keyb, vdst + c8 * 1024);
      }
    };

    asm volatile("s_waitcnt vmcnt(0)" ::: "memory");
    if (nt > 0) stage(kc, vc, 0);

    for (int j = 0; j < nt; ++j) {
      if (j + 1 < nt) {
        stage(kn, vn, (j + 1) * 32);
        asm volatile("s_waitcnt vmcnt(4)" ::: "memory");
      } else {
        asm volatile("s_waitcnt vmcnt(0)" ::: "memory");
      }
      __builtin_amdgcn_s_barrier();

      const int s0 = j * 32;
      // ---- S^T = K Q^T (swapped): sc[rb][c][rr] = S[key=s0+c*16+lg*4+rr][q=rb*16+lr]
      f32x4 sc[2][2];
      sc[0][0] = (f32x4)0.0f; sc[0][1] = (f32x4)0.0f;
      sc[1][0] = (f32x4)0.0f; sc[1][1] = (f32x4)0.0f;
#pragma unroll
      for (int c = 0; c < 2; ++c) {
        const int key = c * 16 + lr;
        const int kx = (key & 7) << 4;
#pragma unroll
        for (int kk = 0; kk < 4; ++kk) {
          const int byte = (key << 8) + ((kk * 32 + lg * 8) << 1);
          bf16x8 kf = *(const bf16x8*)(kc + (byte ^ kx));
          sc[0][c] = __builtin_amdgcn_mfma_f32_16x16x32_bf16(kf, qf[0][kk], sc[0][c], 0, 0, 0);
          sc[1][c] = __builtin_amdgcn_mfma_f32_16x16x32_bf16(kf, qf[1][kk], sc[1][c], 0, 0, 0);
        }
      }

      // ---- mask + online softmax, in-register (row = q = lr per lane)
      const int kbase = s0 + (lg << 2);
      float al_[2];
#pragma unroll
      for (int rb = 0; rb < 2; ++rb) {
        const int lim = t0 + w * 32 + rb * 16 + lr + skv - SQ_;
        float mx = -1e30f;
#pragma unroll
        for (int c = 0; c < 2; ++c)
#pragma unroll
          for (int rr = 0; rr < 4; ++rr) {
            const int key = kbase + c * 16 + rr;
            float sv = (key <= lim) ? sc[rb][c][rr] * SCALE_ : -1e30f;
            sc[rb][c][rr] = sv;
            mx = fmaxf(mx, sv);
          }
        mx = fmaxf(mx, __shfl_xor(mx, 16));
        mx = fmaxf(mx, __shfl_xor(mx, 32));
        const float mn = fmaxf(m_[rb], mx);
        al_[rb] = __expf(m_[rb] - mn);
        m_[rb] = mn;
        float ps = 0.0f;
#pragma unroll
        for (int c = 0; c < 2; ++c)
#pragma unroll
          for (int rr = 0; rr < 4; ++rr) {
            const float p = __expf(sc[rb][c][rr] - mn);
            sc[rb][c][rr] = p;
            ps += p;
          }
        ps += __shfl_xor(ps, 16);
        ps += __shfl_xor(ps, 32);
        l_[rb] = l_[rb] * al_[rb] + ps;
      }

      // ---- rescale acc: alpha lives at q=lr; acc needs q=lg*4+rr
      float alq0[4], alq1[4];
#pragma unroll
      for (int rr = 0; rr < 4; ++rr) {
        alq0[rr] = __shfl(al_[0], lg * 4 + rr, 16);
        alq1[rr] = __shfl(al_[1], lg * 4 + rr, 16);
      }
#pragma unroll
      for (int dd = 0; dd < 8; ++dd)
#pragma unroll
        for (int rr = 0; rr < 4; ++rr) { acc0[dd][rr] *= alq0[rr]; acc1[dd][rr] *= alq1[rr]; }

      // ---- P in-register: pa[rb][c] = P[q=lr][key = c*16 + lg*4 + j] (K=16 A-fragment)
      bf16x4 pa[2][2];
#pragma unroll
      for (int rb = 0; rb < 2; ++rb)
#pragma unroll
        for (int c = 0; c < 2; ++c) {
          const f32x4 s4 = rb ? sc[1][c] : sc[0][c];
          bf16x4 t;
          t[0] = (short)f2bf(s4[0]); t[1] = (short)f2bf(s4[1]);
          t[2] = (short)f2bf(s4[2]); t[3] = (short)f2bf(s4[3]);
          pa[rb][c] = t;
        }

      // ---- O += P V  (two K=16 chunks; V^T b64 fragments k = lg*4+j)
#pragma unroll
      for (int dd = 0; dd < 8; ++dd) {
        const int d = dd * 16 + lr;
#pragma unroll
        for (int c = 0; c < 2; ++c) {
          const int lam = d * 64 + c * 32 + lg * 8;
          bf16x4 vf = *(const bf16x4*)(vc + (lam ^ (((lam >> 7) & 7) << 4)));
          acc0[dd] = mfma_k16(pa[0][c], vf, acc0[dd]);
          acc1[dd] = mfma_k16(pa[1][c], vf, acc1[dd]);
        }
      }
      asm volatile("" ::: "memory");
      __builtin_amdgcn_s_barrier();
      { char* t = kc; kc = kn; kn = t; t = vc; vc = vn; vn = t; }
    }

    // ---- epilogue (l_ lives at q=lr; acc rows are q=lg*4+rr)
    const float* mp = meanv + ((size_t)(b * HK_ + hk)) * D_;
#pragma unroll
    for (int rb = 0; rb < 2; ++rb) {
      const f32x4* acc = rb ? acc1 : acc0;
      const float lsrc = rb ? l_[1] : l_[0];
#pragma unroll
      for (int rr = 0; rr < 4; ++rr) {
        const float lq = __shfl(lsrc, lg * 4 + rr, 16);
        const int t_r = t0 + w * 32 + rb * 16 + lg * 4 + rr;
        const bool deg = (t_r + skv - SQ_) < 0;
        const float inv = 1.0f / lq;
        float* op = out + (((size_t)b * SQ_ + t_r) * H_ + h) * D_;
#pragma unroll
        for (int dd = 0; dd < 8; ++dd) {
          const int d = dd * 16 + lr;
          op[d] = deg ? mp[d] : acc[dd][rr] * inv;
        }
      }
    }
    __syncthreads();  // all waves done with LDS/regs before next grab
  }
}

extern "C" void kernel_launch(void* const* d_in, const int* in_sizes, int n_in,
                              void* d_out, int out_size, void* d_ws, size_t ws_size,
                              hipStream_t stream) {
  const float* q = (const float*)d_in[0];
  const float* kv = (const float*)d_in[1];
  const void* mask = d_in[2];
  float* out = (float*)d_out;

  const size_t KB_OFF = 0;
  const size_t VT_OFF = 8ull * 1024 * 1024;
  const size_t MV_OFF = 16ull * 1024 * 1024;
  unsigned short* Kb = (unsigned short*)((char*)d_ws + KB_OFF);
  unsigned short* VTb = (unsigned short*)((char*)d_ws + VT_OFF);
  float* meanv = (float*)((char*)d_ws + MV_OFF);
  int* skv = (int*)((char*)d_ws + MV_OFF + 8192);
  int* work_ctr = (int*)((char*)d_ws + MV_OFF + 8192 + 64);

  hipMemsetAsync((char*)d_ws + MV_OFF, 0, 8192 + 128, stream);
  skv_kernel<<<B_, 256, 0, stream>>>(mask, skv);
  convk<<<dim3(SK_ / 16, HK_, B_), 256, 0, stream>>>(kv, Kb);
  convvt<<<dim3(SK_ / 64, HK_, B_), 256, 0, stream>>>(kv, VTb);
  meanv_kernel<<<B_ * HK_ * 16, 128, 0, stream>>>(kv, meanv);
  flash8<<<dim3(1024), 256, 0, stream>>>(q, Kb, VTb, skv, meanv, out, work_ctr);
}